// Round 1
// baseline (617.939 us; speedup 1.0000x reference)
//
#include <hip/hip_runtime.h>

typedef __bf16 bf16x8 __attribute__((ext_vector_type(8)));
typedef float  f32x4  __attribute__((ext_vector_type(4)));
typedef unsigned short u16x8 __attribute__((ext_vector_type(8)));

__device__ __forceinline__ float b2f(unsigned short u) {
    unsigned int x = ((unsigned int)u) << 16;
    float f; __builtin_memcpy(&f, &x, 4); return f;
}
__device__ __forceinline__ unsigned short f2b(float f) {
    unsigned int x; __builtin_memcpy(&x, &f, 4);
    unsigned int r = (x + 0x7FFFu + ((x >> 16) & 1u)) >> 16;
    return (unsigned short)r;
}
__device__ __forceinline__ void async16(void* lds, const void* g) {
    __builtin_amdgcn_global_load_lds((const __attribute__((address_space(1))) void*)g,
                                     (__attribute__((address_space(3))) void*)lds, 16, 0, 0);
}

// ---------------------------------------------------------------------------
// K1: LN(m) -> v = mhat@Wv.T (bf16, per-head transposed layout vT[h][c=n*8+d][j])
//              g = sigmoid(mhat@Wg.T) (bf16, standard layout g[(i*512+n)*64+h*8+d])
// block = (n, s-chunk of 32); 4 waves, wave handles 8 rows (s = j = i index of m).
// ---------------------------------------------------------------------------
__global__ __launch_bounds__(256) void k1_ln_vg(
    const float* __restrict__ m, const float* __restrict__ lnw, const float* __restrict__ lnb,
    const float* __restrict__ Wv, const float* __restrict__ Wg,
    unsigned short* __restrict__ vT, unsigned short* __restrict__ gB)
{
    __shared__ float vstage[32][65];
    __shared__ float mh[4][64];
    const int t = threadIdx.x, w = t >> 6, lane = t & 63;
    const int n = blockIdx.x;
    const int s0 = blockIdx.y * 32;

    float wv[64], wg[64];
#pragma unroll
    for (int q = 0; q < 16; q++) {
        float4 a = *(const float4*)&Wv[lane * 64 + q * 4];
        wv[4*q+0]=a.x; wv[4*q+1]=a.y; wv[4*q+2]=a.z; wv[4*q+3]=a.w;
        float4 b = *(const float4*)&Wg[lane * 64 + q * 4];
        wg[4*q+0]=b.x; wg[4*q+1]=b.y; wg[4*q+2]=b.z; wg[4*q+3]=b.w;
    }
    const float lw = lnw[lane], lb = lnb[lane];

    for (int rr = 0; rr < 8; rr++) {
        const int rl = w * 8 + rr;
        const int s  = s0 + rl;
        float x = m[((size_t)s * 512 + n) * 64 + lane];
        float sum = x, sq = x * x;
#pragma unroll
        for (int msk = 32; msk; msk >>= 1) { sum += __shfl_xor(sum, msk); sq += __shfl_xor(sq, msk); }
        float mu = sum * (1.f / 64.f);
        float var = sq * (1.f / 64.f) - mu * mu;
        float rs = rsqrtf(var + 1e-5f);
        float mhv = (x - mu) * rs * lw + lb;
        mh[w][lane] = mhv;
        float av = 0.f, ag = 0.f;
#pragma unroll
        for (int q = 0; q < 16; q++) {
            float4 mm = *(float4*)&mh[w][q * 4];  // wave-uniform broadcast
            av += mm.x*wv[4*q] + mm.y*wv[4*q+1] + mm.z*wv[4*q+2] + mm.w*wv[4*q+3];
            ag += mm.x*wg[4*q] + mm.y*wg[4*q+1] + mm.z*wg[4*q+2] + mm.w*wg[4*q+3];
        }
        vstage[rl][lane] = av;
        float gg = 1.f / (1.f + __expf(-ag));
        gB[((size_t)s * 512 + n) * 64 + lane] = f2b(gg);
    }
    __syncthreads();
    // transpose-write v: thread t -> (h = t>>5, d = (t>>2)&7, jc = t&3), 8 j's contiguous
    const int h = t >> 5, d = (t >> 2) & 7, jc = t & 3;
    u16x8 pk;
#pragma unroll
    for (int u = 0; u < 8; u++) pk[u] = f2b(vstage[jc * 8 + u][h * 8 + d]);
    size_t off = (size_t)h * 2097152 + (size_t)(n * 8 + d) * 512 + (size_t)(s0 + jc * 8);
    *(u16x8*)(vT + off) = pk;
}

// ---------------------------------------------------------------------------
// K2: LN(z) row (128) -> logits b[i][j][h] fp32.  wave per row; W_b in regs
// lane = (h = lane&7, cg = lane>>3): partial dot over 16 c's, xor-reduce 8/16/32.
// ---------------------------------------------------------------------------
__global__ __launch_bounds__(256) void k2_ln_b(
    const float* __restrict__ z, const float* __restrict__ lnw, const float* __restrict__ lnb,
    const float* __restrict__ Wb, float* __restrict__ bL)
{
    __shared__ float zrow[4][132];
    const int t = threadIdx.x, w = t >> 6, lane = t & 63;
    const int h = lane & 7, cg = lane >> 3;
    float wb[16];
#pragma unroll
    for (int q = 0; q < 4; q++) {
        float4 a = *(const float4*)&Wb[h * 128 + cg * 16 + q * 4];
        wb[4*q+0]=a.x; wb[4*q+1]=a.y; wb[4*q+2]=a.z; wb[4*q+3]=a.w;
    }
    const float lw0 = lnw[lane], lw1 = lnw[64 + lane];
    const float lb0 = lnb[lane], lb1 = lnb[64 + lane];
    const int nw = gridDim.x * 4;
    for (int row = blockIdx.x * 4 + w; row < 262144; row += nw) {
        float x0 = z[(size_t)row * 128 + lane];
        float x1 = z[(size_t)row * 128 + 64 + lane];
        float sum = x0 + x1, sq = x0 * x0 + x1 * x1;
#pragma unroll
        for (int msk = 32; msk; msk >>= 1) { sum += __shfl_xor(sum, msk); sq += __shfl_xor(sq, msk); }
        float mu = sum * (1.f / 128.f);
        float var = sq * (1.f / 128.f) - mu * mu;
        float rs = rsqrtf(var + 1e-5f);
        zrow[w][lane]      = (x0 - mu) * rs * lw0 + lb0;
        zrow[w][64 + lane] = (x1 - mu) * rs * lw1 + lb1;
        float acc = 0.f;
#pragma unroll
        for (int q = 0; q < 4; q++) {
            float4 zz = *(float4*)&zrow[w][cg * 16 + q * 4];
            acc += zz.x*wb[4*q] + zz.y*wb[4*q+1] + zz.z*wb[4*q+2] + zz.w*wb[4*q+3];
        }
#pragma unroll
        for (int msk = 8; msk < 64; msk <<= 1) acc += __shfl_xor(acc, msk);
        if (lane < 8) bL[(size_t)row * 8 + lane] = acc;
    }
}

// ---------------------------------------------------------------------------
// K3: softmax over j per (i,h); reads b[i][j][h], writes w bf16 planar wp[h][i][j].
// block per i; 32-thread group per h.
// ---------------------------------------------------------------------------
__global__ __launch_bounds__(256) void k3_softmax(
    const float* __restrict__ bL, unsigned short* __restrict__ wp)
{
    __shared__ float bl[8][520];
    const int t = threadIdx.x;
    const int i = blockIdx.x;
    const float* src = bL + (size_t)i * 4096;
#pragma unroll
    for (int q = 0; q < 4; q++) {
        float4 a = *(const float4*)&src[q * 1024 + t * 4];
        int idx = q * 1024 + t * 4;
        bl[(idx+0)&7][(idx+0)>>3] = a.x;
        bl[(idx+1)&7][(idx+1)>>3] = a.y;
        bl[(idx+2)&7][(idx+2)>>3] = a.z;
        bl[(idx+3)&7][(idx+3)>>3] = a.w;
    }
    __syncthreads();
    const int h = t >> 5, l32 = t & 31;
    float vals[16];
    float mx = -1e30f;
#pragma unroll
    for (int jj = 0; jj < 16; jj++) { vals[jj] = bl[h][l32 + 32 * jj]; mx = fmaxf(mx, vals[jj]); }
#pragma unroll
    for (int msk = 1; msk < 32; msk <<= 1) mx = fmaxf(mx, __shfl_xor(mx, msk, 32));
    float s = 0.f;
#pragma unroll
    for (int jj = 0; jj < 16; jj++) { vals[jj] = __expf(vals[jj] - mx); s += vals[jj]; }
#pragma unroll
    for (int msk = 1; msk < 32; msk <<= 1) s += __shfl_xor(s, msk, 32);
    const float inv = 1.f / s;
    unsigned short* dst = wp + (size_t)h * 262144 + (size_t)i * 512;
#pragma unroll
    for (int jj = 0; jj < 16; jj++) dst[l32 + 32 * jj] = f2b(vals[jj] * inv);
}

// ---------------------------------------------------------------------------
// K4: per-head GEMM o_h[i][c] = w_h[i][:] @ vT_h[c][:]^T  (K=j=512), bf16 MFMA
// 128x128 tile, 4 waves, 16x16x32 frags; epilogue fuses g-gate, writes go bf16.
// ---------------------------------------------------------------------------
__global__ __launch_bounds__(256) void k4_einsum(
    const unsigned short* __restrict__ wp, const unsigned short* __restrict__ vT,
    const unsigned short* __restrict__ gB, unsigned short* __restrict__ go)
{
    __shared__ __align__(16) unsigned short As[128 * 32];
    __shared__ __align__(16) unsigned short Bs[128 * 32];
    const int t = threadIdx.x;
    const int c0 = blockIdx.x * 128, i0 = blockIdx.y * 128, h = blockIdx.z;
    const unsigned short* Ab = wp + (size_t)h * 262144;
    const unsigned short* Bb = vT + (size_t)h * 2097152;
    const int w = t >> 6, lane = t & 63, quad = lane >> 4, lq = lane & 15;
    const int wi = w >> 1, wc = w & 1;

    f32x4 zero = {0.f, 0.f, 0.f, 0.f};
    f32x4 acc[4][4];
#pragma unroll
    for (int mi = 0; mi < 4; mi++)
#pragma unroll
        for (int ni = 0; ni < 4; ni++) acc[mi][ni] = zero;

    for (int k0 = 0; k0 < 512; k0 += 32) {
#pragma unroll
        for (int r = 0; r < 2; r++) {
            int idx = r * 256 + t;
            int row = idx >> 2, q = idx & 3;
            async16(&As[idx * 8], Ab + (size_t)(i0 + row) * 512 + k0 + q * 8);
            async16(&Bs[idx * 8], Bb + (size_t)(c0 + row) * 512 + k0 + q * 8);
        }
        __syncthreads();
        bf16x8 af[4], bfr[4];
#pragma unroll
        for (int mi = 0; mi < 4; mi++)
            af[mi] = *(const bf16x8*)&As[(wi * 64 + mi * 16 + lq) * 32 + quad * 8];
#pragma unroll
        for (int ni = 0; ni < 4; ni++)
            bfr[ni] = *(const bf16x8*)&Bs[(wc * 64 + ni * 16 + lq) * 32 + quad * 8];
#pragma unroll
        for (int mi = 0; mi < 4; mi++)
#pragma unroll
            for (int ni = 0; ni < 4; ni++)
                acc[mi][ni] = __builtin_amdgcn_mfma_f32_16x16x32_bf16(af[mi], bfr[ni], acc[mi][ni], 0, 0, 0);
        __syncthreads();
    }
    // epilogue: go = g * o, standard layout [(i*512+n)*64 + h*8 + d]
#pragma unroll
    for (int mi = 0; mi < 4; mi++)
#pragma unroll
        for (int ni = 0; ni < 4; ni++)
#pragma unroll
            for (int rr = 0; rr < 4; rr++) {
                int ii = i0 + wi * 64 + mi * 16 + quad * 4 + rr;
                int c  = c0 + wc * 64 + ni * 16 + lq;
                size_t off = ((size_t)ii * 512 + (c >> 3)) * 64 + h * 8 + (c & 7);
                float gv = b2f(gB[off]);
                go[off] = f2b(acc[mi][ni][rr] * gv);
            }
}

// ---------------------------------------------------------------------------
// K5: out = go @ W_out.T (fp32 out).  wave per row; W_out rows in regs.
// ---------------------------------------------------------------------------
__global__ __launch_bounds__(256) void k5_out(
    const unsigned short* __restrict__ go, const float* __restrict__ Wo, float* __restrict__ out)
{
    __shared__ float grow[4][64];
    const int t = threadIdx.x, w = t >> 6, lane = t & 63;
    float wo[64];
#pragma unroll
    for (int q = 0; q < 16; q++) {
        float4 a = *(const float4*)&Wo[lane * 64 + q * 4];
        wo[4*q+0]=a.x; wo[4*q+1]=a.y; wo[4*q+2]=a.z; wo[4*q+3]=a.w;
    }
    const int nw = gridDim.x * 4;
    for (int row = blockIdx.x * 4 + w; row < 262144; row += nw) {
        grow[w][lane] = b2f(go[(size_t)row * 64 + lane]);
        float acc = 0.f;
#pragma unroll
        for (int q = 0; q < 16; q++) {
            float4 gg = *(float4*)&grow[w][q * 4];  // wave-uniform broadcast
            acc += gg.x*wo[4*q] + gg.y*wo[4*q+1] + gg.z*wo[4*q+2] + gg.w*wo[4*q+3];
        }
        out[(size_t)row * 64 + lane] = acc;
    }
}

extern "C" void kernel_launch(void* const* d_in, const int* in_sizes, int n_in,
                              void* d_out, int out_size, void* d_ws, size_t ws_size,
                              hipStream_t stream)
{
    (void)in_sizes; (void)n_in; (void)out_size; (void)ws_size;
    const float* m    = (const float*)d_in[0];
    const float* z    = (const float*)d_in[1];
    const float* lnmw = (const float*)d_in[2];
    const float* lnmb = (const float*)d_in[3];
    const float* lnzw = (const float*)d_in[4];
    const float* lnzb = (const float*)d_in[5];
    const float* Wv   = (const float*)d_in[6];
    const float* Wb   = (const float*)d_in[7];
    const float* Wg   = (const float*)d_in[8];
    const float* Wo   = (const float*)d_in[9];
    float* out = (float*)d_out;
    char* ws = (char*)d_ws;

    unsigned short* vT = (unsigned short*)(ws);              // 8*4096*512*2  = 32 MiB
    unsigned short* wp = (unsigned short*)(ws + 33554432);   // 8*512*512*2   =  4 MiB
    unsigned short* gB = (unsigned short*)(ws + 37748736);   // 512*512*64*2  = 32 MiB
    float*          bL = (float*)(ws + 71303168);            // 512*512*8*4   =  8 MiB
    unsigned short* go = (unsigned short*)(ws + 79691776);   // 512*512*64*2  = 32 MiB

    k1_ln_vg  <<<dim3(512, 16), 256, 0, stream>>>(m, lnmw, lnmb, Wv, Wg, vT, gB);
    k2_ln_b   <<<dim3(1024),    256, 0, stream>>>(z, lnzw, lnzb, Wb, bL);
    k3_softmax<<<dim3(512),     256, 0, stream>>>(bL, wp);
    k4_einsum <<<dim3(32, 4, 8),256, 0, stream>>>(wp, vT, gB, go);
    k5_out    <<<dim3(2048),    256, 0, stream>>>(go, Wo, out);
}